// Round 13
// baseline (57.556 us; speedup 1.0000x reference)
//
#include <hip/hip_runtime.h>
#include <stdint.h>

typedef __bf16 bf16;
typedef __attribute__((ext_vector_type(8))) __bf16 bfx8;
typedef __attribute__((ext_vector_type(4))) float f32x4;

__device__ inline f32x4 mfma16(bfx8 a, bfx8 b, f32x4 c) {
  return __builtin_amdgcn_mfma_f32_16x16x32_bf16(a, b, c, 0, 0, 0);
}

// Async 16B global->LDS (chunk_out Q/K staging).
__device__ inline void gl16(const bf16* g, bf16* lbase, int lane) {
#if __has_builtin(__builtin_amdgcn_global_load_lds)
  (void)lane;
  __builtin_amdgcn_global_load_lds(
      (const __attribute__((address_space(1))) void*)g,
      (__attribute__((address_space(3))) void*)lbase, 16, 0, 0);
#else
  *(bfx8*)(lbase + lane * 8) = *(const bfx8*)g;
#endif
}

// Image convention: 64x64 bf16 tile stored as 4096 elems, 16B chunks
// XOR-swizzled per row: element (i,e) lives at i*64 + (((e>>3)^(i&7))<<3) + (e&7).
__device__ inline int img_off(int i, int e) {
  return i * 64 + ((((e >> 3) ^ (i & 7)) << 3)) + (e & 7);
}

__device__ inline bfx8 cvt8(const float* s) {
  f32x4 x0 = *(const f32x4*)s, x1 = *(const f32x4*)(s + 4);
  bfx8 v;
  v[0] = (bf16)x0[0]; v[1] = (bf16)x0[1]; v[2] = (bf16)x0[2]; v[3] = (bf16)x0[3];
  v[4] = (bf16)x1[0]; v[5] = (bf16)x1[1]; v[6] = (bf16)x1[2]; v[7] = (bf16)x1[3];
  return v;
}

struct ProjArgs {
  const float *Q, *K, *V, *Wq, *Wk, *Wv;
  bf16 *Qimg, *Kimg, *Vimg, *KVb;
  float* ksums;
};

// 512 blocks: even bid -> Q-proj (256 tiles), odd bid -> fused KV-proj+state.
// LDS arena 41984 B: [0,8K)=As/VT0, [8K,16K)=Bs lo/VT1, [8K,24K)=Bs,
// [24K,32K)=KT0, [32K,40K)=KT1, [40K,41K)=ksum_p.
__global__ __launch_bounds__(256) void proj_fused(ProjArgs pa) {
  const int tid = threadIdx.x, l = tid & 63, w = tid >> 6;
  const int wm = w >> 1, wn = w & 1, lm = l & 15, lk = l >> 4;
  __shared__ __align__(16) char smem[41984];
  bf16* As = (bf16*)smem;
  bf16* Bs = (bf16*)(smem + 8192);

  const int bid = blockIdx.x;
  const int idx = bid >> 1;

  if ((bid & 1) == 0) {
    // ---------------- Q projection + phi -> Qimg ----------------
    const int tm = (idx >> 2) * 64, tn = (idx & 3) * 128;
    f32x4 acc[2][4] = {};
    for (int kt = 0; kt < 8; ++kt) {
#pragma unroll
      for (int it = 0; it < 4; ++it) {
        int c = it * 256 + tid, row = c >> 3, t8 = c & 7;
        bfx8 v = cvt8(pa.Wq + (size_t)(tn + row) * 512 + kt * 64 + t8 * 8);
        *(bfx8*)&Bs[row * 64 + ((t8 ^ (row & 7)) << 3)] = v;
      }
#pragma unroll
      for (int it = 0; it < 2; ++it) {
        int c = it * 256 + tid, row = c >> 3, t8 = c & 7;
        bfx8 v = cvt8(pa.Q + (size_t)(tm + row) * 512 + kt * 64 + t8 * 8);
        *(bfx8*)&As[row * 64 + ((t8 ^ (row & 7)) << 3)] = v;
      }
      __syncthreads();
#pragma unroll
      for (int ks = 0; ks < 2; ++ks) {
        bfx8 af[2], bfr[4];
#pragma unroll
        for (int i = 0; i < 2; ++i) {
          int ra = wm * 32 + i * 16 + lm;
          af[i] = *(const bfx8*)&As[ra * 64 + (((ks * 4 + lk) ^ (ra & 7)) << 3)];
        }
#pragma unroll
        for (int j = 0; j < 4; ++j) {
          int rb = wn * 64 + j * 16 + lm;
          bfr[j] = *(const bfx8*)&Bs[rb * 64 + (((ks * 4 + lk) ^ (rb & 7)) << 3)];
        }
#pragma unroll
        for (int i = 0; i < 2; ++i)
#pragma unroll
          for (int j = 0; j < 4; ++j)
            acc[i][j] = mfma16(af[i], bfr[j], acc[i][j]);
      }
      __syncthreads();
    }
#pragma unroll
    for (int i = 0; i < 2; ++i)
#pragma unroll
      for (int j = 0; j < 4; ++j)
#pragma unroll
        for (int r = 0; r < 4; ++r) {
          int m = tm + wm * 32 + i * 16 + lk * 4 + r;
          int n = tn + wn * 64 + j * 16 + lm;
          float v = acc[i][j][r];
          v = v > 0.f ? v + 1.f : __expf(v);
          pa.Qimg[((size_t)((m >> 6) * 8 + (n >> 6)) << 12) + img_off(m & 63, n & 63)] =
              (bf16)v;
        }
    return;
  }

  // ---------------- fused K,V projection + per-chunk KV state ----------------
  const int rt = idx >> 2, ty = idx & 3;  // row-tile (=(b,c)), head-pair
  const int tm = rt * 64, tn = ty * 128;
  bf16* VT0 = (bf16*)smem;
  bf16* VT1 = (bf16*)(smem + 8192);
  bf16* KT0 = (bf16*)(smem + 24576);
  bf16* KT1 = (bf16*)(smem + 32768);
  float* ksum_p = (float*)(smem + 40960);

  f32x4 acc[2][4];

  // --- K GEMM ---
#pragma unroll
  for (int i = 0; i < 2; ++i)
#pragma unroll
    for (int j = 0; j < 4; ++j) acc[i][j] = (f32x4){0.f, 0.f, 0.f, 0.f};
  for (int kt = 0; kt < 8; ++kt) {
#pragma unroll
    for (int it = 0; it < 4; ++it) {
      int c = it * 256 + tid, row = c >> 3, t8 = c & 7;
      bfx8 v = cvt8(pa.Wk + (size_t)(tn + row) * 512 + kt * 64 + t8 * 8);
      *(bfx8*)&Bs[row * 64 + ((t8 ^ (row & 7)) << 3)] = v;
    }
#pragma unroll
    for (int it = 0; it < 2; ++it) {
      int c = it * 256 + tid, row = c >> 3, t8 = c & 7;
      bfx8 v = cvt8(pa.K + (size_t)(tm + row) * 512 + kt * 64 + t8 * 8);
      *(bfx8*)&As[row * 64 + ((t8 ^ (row & 7)) << 3)] = v;
    }
    __syncthreads();
#pragma unroll
    for (int ks = 0; ks < 2; ++ks) {
      bfx8 af[2], bfr[4];
#pragma unroll
      for (int i = 0; i < 2; ++i) {
        int ra = wm * 32 + i * 16 + lm;
        af[i] = *(const bfx8*)&As[ra * 64 + (((ks * 4 + lk) ^ (ra & 7)) << 3)];
      }
#pragma unroll
      for (int j = 0; j < 4; ++j) {
        int rb = wn * 64 + j * 16 + lm;
        bfr[j] = *(const bfx8*)&Bs[rb * 64 + (((ks * 4 + lk) ^ (rb & 7)) << 3)];
      }
#pragma unroll
      for (int i = 0; i < 2; ++i)
#pragma unroll
        for (int j = 0; j < 4; ++j)
          acc[i][j] = mfma16(af[i], bfr[j], acc[i][j]);
    }
    __syncthreads();
  }
  // epilogue K: phi -> Kimg + KT LDS tiles ([24K,40K) untouched by staging)
  {
    bf16* KTl = wn ? KT1 : KT0;
#pragma unroll
    for (int i = 0; i < 2; ++i)
#pragma unroll
      for (int jj = 0; jj < 4; ++jj)
#pragma unroll
        for (int r = 0; r < 4; ++r) {
          int ml = wm * 32 + i * 16 + lk * 4 + r;  // chunk row j
          int dl = jj * 16 + lm;                   // head-local d
          float v = acc[i][jj][r];
          v = v > 0.f ? v + 1.f : __expf(v);
          bf16 bv = (bf16)v;
          KTl[dl * 64 + (((ml >> 3) ^ (dl & 7)) << 3) + (ml & 7)] = bv;
          pa.Kimg[((size_t)(rt * 8 + 2 * ty + wn) << 12) + img_off(ml, dl)] = bv;
        }
  }
  __syncthreads();

  // --- V GEMM (reuses acc + staging) ---
#pragma unroll
  for (int i = 0; i < 2; ++i)
#pragma unroll
    for (int j = 0; j < 4; ++j) acc[i][j] = (f32x4){0.f, 0.f, 0.f, 0.f};
  for (int kt = 0; kt < 8; ++kt) {
#pragma unroll
    for (int it = 0; it < 4; ++it) {
      int c = it * 256 + tid, row = c >> 3, t8 = c & 7;
      bfx8 v = cvt8(pa.Wv + (size_t)(tn + row) * 512 + kt * 64 + t8 * 8);
      *(bfx8*)&Bs[row * 64 + ((t8 ^ (row & 7)) << 3)] = v;
    }
#pragma unroll
    for (int it = 0; it < 2; ++it) {
      int c = it * 256 + tid, row = c >> 3, t8 = c & 7;
      bfx8 v = cvt8(pa.V + (size_t)(tm + row) * 512 + kt * 64 + t8 * 8);
      *(bfx8*)&As[row * 64 + ((t8 ^ (row & 7)) << 3)] = v;
    }
    __syncthreads();
#pragma unroll
    for (int ks = 0; ks < 2; ++ks) {
      bfx8 af[2], bfr[4];
#pragma unroll
      for (int i = 0; i < 2; ++i) {
        int ra = wm * 32 + i * 16 + lm;
        af[i] = *(const bfx8*)&As[ra * 64 + (((ks * 4 + lk) ^ (ra & 7)) << 3)];
      }
#pragma unroll
      for (int j = 0; j < 4; ++j) {
        int rb = wn * 64 + j * 16 + lm;
        bfr[j] = *(const bfx8*)&Bs[rb * 64 + (((ks * 4 + lk) ^ (rb & 7)) << 3)];
      }
#pragma unroll
      for (int i = 0; i < 2; ++i)
#pragma unroll
        for (int j = 0; j < 4; ++j)
          acc[i][j] = mfma16(af[i], bfr[j], acc[i][j]);
    }
    __syncthreads();
  }
  // epilogue V: -> Vimg + VT LDS tiles (overwrites staging region, post-sync)
  {
    bf16* VTl = wn ? VT1 : VT0;
#pragma unroll
    for (int i = 0; i < 2; ++i)
#pragma unroll
      for (int jj = 0; jj < 4; ++jj)
#pragma unroll
        for (int r = 0; r < 4; ++r) {
          int ml = wm * 32 + i * 16 + lk * 4 + r;
          int dl = jj * 16 + lm;
          bf16 bv = (bf16)acc[i][jj][r];
          VTl[dl * 64 + (((ml >> 3) ^ (dl & 7)) << 3) + (ml & 7)] = bv;
          pa.Vimg[((size_t)(rt * 8 + 2 * ty + wn) << 12) + img_off(ml, dl)] = bv;
        }
  }
  __syncthreads();

  // --- per-head chunk state: KV^T[e][d] = sum_j V[j][e]*Kf[j][d], ksum[d] ---
  const int b = rt >> 4, c = rt & 15;
#pragma unroll
  for (int hh = 0; hh < 2; ++hh) {
    const bf16* KTl = hh ? KT1 : KT0;
    const bf16* VTl = hh ? VT1 : VT0;
    {
      int d = tid & 63, jp = tid >> 6;
      float s = 0.f;
#pragma unroll
      for (int q = 0; q < 16; ++q) {
        int j = jp * 16 + q;
        s += (float)KTl[d * 64 + (((j >> 3) ^ (d & 7)) << 3) + (j & 7)];
      }
      ksum_p[jp * 64 + d] = s;
    }
    f32x4 kacc[4] = {};
#pragma unroll
    for (int ks = 0; ks < 2; ++ks) {
      int r = w * 16 + lm;
      bfx8 av = *(const bfx8*)&VTl[r * 64 + (((ks * 4 + lk) ^ (r & 7)) << 3)];
#pragma unroll
      for (int bn = 0; bn < 4; ++bn) {
        int e = bn * 16 + lm;
        bfx8 bk = *(const bfx8*)&KTl[e * 64 + (((ks * 4 + lk) ^ (e & 7)) << 3)];
        kacc[bn] = mfma16(av, bk, kacc[bn]);
      }
    }
    const int bh = b * 8 + 2 * ty + hh;
    bf16* st = pa.KVb + (size_t)(bh * 16 + c) * 4096;
#pragma unroll
    for (int bn = 0; bn < 4; ++bn)
#pragma unroll
      for (int rg = 0; rg < 4; ++rg) {
        int e = w * 16 + lk * 4 + rg, d = bn * 16 + lm;
        st[e * 64 + d] = (bf16)kacc[bn][rg];
      }
    __syncthreads();
    if (tid < 64)
      pa.ksums[(size_t)(bh * 16 + c) * 64 + tid] =
          ksum_p[tid] + ksum_p[64 + tid] + ksum_p[128 + tid] + ksum_p[192 + tid];
    __syncthreads();
  }
}

// ---------------- attention stage 2: per-chunk output ----------------
__global__ __launch_bounds__(256) void chunk_out(const bf16* __restrict__ Qimg,
                                                 const bf16* __restrict__ Kimg,
                                                 const bf16* __restrict__ Vimg,
                                                 const bf16* __restrict__ KVb,
                                                 const float* __restrict__ ksums,
                                                 bf16* __restrict__ Obsw) {
  const int bh = blockIdx.x, c = blockIdx.y, b = bh >> 3, h = bh & 7;
  const int tid = threadIdx.x, l = tid & 63, w = tid >> 6, lm = l & 15, lk = l >> 4;

  __shared__ __align__(16) bf16 Qs[64 * 64];
  __shared__ __align__(16) bf16 Ks[64 * 64];
  __shared__ __align__(16) bf16 VTs[64 * 64];
  __shared__ __align__(16) bf16 Ss[64 * 64];
  __shared__ __align__(16) bf16 KVL[64 * 64];
  __shared__ float ksum[64], den_i[64], den_all[64], den_p[256];

  const size_t tb = (size_t)((b * 16 + c) * 8 + h) << 12;
  const int sr = tid >> 2, sp = tid & 3;

#pragma unroll
  for (int q = 0; q < 2; ++q) {
    int cb = (q * 4 + w) * 64;
    gl16(Qimg + tb + (size_t)(cb + l) * 8, &Qs[cb * 8], l);
    gl16(Kimg + tb + (size_t)(cb + l) * 8, &Ks[cb * 8], l);
  }
  {
    const bf16* Vt = Vimg + tb;
    bfx8 v0 = *(const bfx8*)&Vt[sr * 64 + (((2 * sp) ^ (sr & 7)) << 3)];
    bfx8 v1 = *(const bfx8*)&Vt[sr * 64 + (((2 * sp + 1) ^ (sr & 7)) << 3)];
#pragma unroll
    for (int q = 0; q < 8; ++q) {
      int d0 = sp * 16 + q, d1 = sp * 16 + 8 + q;
      VTs[d0 * 64 + (((sr >> 3) ^ (d0 & 7)) << 3) + (sr & 7)] = v0[q];
      VTs[d1 * 64 + (((sr >> 3) ^ (d1 & 7)) << 3) + (sr & 7)] = v1[q];
    }
  }
  {
    const int e = sr, dp = sp * 16;
    float s0[8] = {}, s1[8] = {};
    const bf16* kb = KVb + (size_t)(bh * 16) * 4096 + e * 64 + dp;
    for (int cc = 0; cc < c; ++cc) {
      bfx8 x0 = *(const bfx8*)(kb + (size_t)cc * 4096);
      bfx8 x1 = *(const bfx8*)(kb + (size_t)cc * 4096 + 8);
#pragma unroll
      for (int q = 0; q < 8; ++q) { s0[q] += (float)x0[q]; s1[q] += (float)x1[q]; }
    }
    bfx8 y0, y1;
#pragma unroll
    for (int q = 0; q < 8; ++q) { y0[q] = (bf16)s0[q]; y1[q] = (bf16)s1[q]; }
    *(bfx8*)&KVL[e * 64 + (((2 * sp) ^ (e & 7)) << 3)] = y0;
    *(bfx8*)&KVL[e * 64 + (((2 * sp + 1) ^ (e & 7)) << 3)] = y1;
    if (tid < 64) {
      float s = 0.f;
      const float* kp = ksums + (size_t)(bh * 16) * 64 + tid;
      for (int cc = 0; cc < c; ++cc) s += kp[(size_t)cc * 64];
      ksum[tid] = s;
    }
  }
  __syncthreads();

  f32x4 sacc[4] = {};
  bfx8 aq[2];
#pragma unroll
  for (int ks = 0; ks < 2; ++ks) {
    int r = w * 16 + lm;
    aq[ks] = *(const bfx8*)&Qs[r * 64 + (((ks * 4 + lk) ^ (r & 7)) << 3)];
#pragma unroll
    for (int bn = 0; bn < 4; ++bn) {
      int rb = bn * 16 + lm;
      bfx8 bk = *(const bfx8*)&Ks[rb * 64 + (((ks * 4 + lk) ^ (rb & 7)) << 3)];
      sacc[bn] = mfma16(aq[ks], bk, sacc[bn]);
    }
  }
  float prs[4] = {0.f, 0.f, 0.f, 0.f};
#pragma unroll
  for (int bn = 0; bn < 4; ++bn)
#pragma unroll
    for (int rg = 0; rg < 4; ++rg) {
      int i = w * 16 + lk * 4 + rg, j = bn * 16 + lm;
      float v = (j <= i) ? sacc[bn][rg] : 0.f;
      prs[rg] += v;
      Ss[i * 64 + (((j >> 3) ^ (i & 7)) << 3) + (j & 7)] = (bf16)v;
    }
#pragma unroll
  for (int m = 1; m < 16; m <<= 1) {
#pragma unroll
    for (int rg = 0; rg < 4; ++rg) prs[rg] += __shfl_xor(prs[rg], m, 64);
  }
  if (lm == 0) {
#pragma unroll
    for (int rg = 0; rg < 4; ++rg) den_i[w * 16 + lk * 4 + rg] = prs[rg];
  }
  {
    float s = 0.f;
#pragma unroll
    for (int q = 0; q < 16; ++q) {
      int d = sp * 16 + q;
      s += (float)Qs[sr * 64 + (((d >> 3) ^ (sr & 7)) << 3) + (d & 7)] * ksum[d];
    }
    den_p[sp * 64 + sr] = s;
  }
  __syncthreads();

  if (tid < 64)
    den_all[tid] = den_i[tid] + den_p[tid] + den_p[64 + tid] + den_p[128 + tid] + den_p[192 + tid];
  f32x4 oacc[4] = {};
#pragma unroll
  for (int ks = 0; ks < 2; ++ks) {
    int r = w * 16 + lm;
    bfx8 as_ = *(const bfx8*)&Ss[r * 64 + (((ks * 4 + lk) ^ (r & 7)) << 3)];
#pragma unroll
    for (int bn = 0; bn < 4; ++bn) {
      int e = bn * 16 + lm;
      bfx8 bv = *(const bfx8*)&VTs[e * 64 + (((ks * 4 + lk) ^ (e & 7)) << 3)];
      oacc[bn] = mfma16(as_, bv, oacc[bn]);
      bfx8 bkv = *(const bfx8*)&KVL[e * 64 + (((ks * 4 + lk) ^ (e & 7)) << 3)];
      oacc[bn] = mfma16(aq[ks], bkv, oacc[bn]);
    }
  }
  __syncthreads();

  bf16* ot = Obsw + tb;
#pragma unroll
  for (int bn = 0; bn < 4; ++bn)
#pragma unroll
    for (int rg = 0; rg < 4; ++rg) {
      int i = w * 16 + lk * 4 + rg, e = bn * 16 + lm;
      float o = oacc[bn][rg] / (den_all[i] + 1e-6f);
      ot[img_off(i, e)] = (bf16)o;
    }
}

// ---------------- output GEMM: out = Obsw @ Wo^T (fp32 out) ----------------
__global__ __launch_bounds__(256) void out_gemm(const bf16* __restrict__ Obsw,
                                                const float* __restrict__ Wo,
                                                float* __restrict__ out) {
  const int bid = blockIdx.x;
  const int tm = (bid >> 2) * 64, tn = (bid & 3) * 128;
  const int tid = threadIdx.x, l = tid & 63, w = tid >> 6;
  const int wm = w >> 1, wn = w & 1, lm = l & 15, lk = l >> 4;

  __shared__ __align__(16) bf16 As[64 * 64];
  __shared__ __align__(16) bf16 Bs[128 * 64];
  f32x4 acc[2][4] = {};

  for (int kt = 0; kt < 8; ++kt) {
#pragma unroll
    for (int it = 0; it < 4; ++it) {
      int c = it * 256 + tid, row = c >> 3, t8 = c & 7;
      bfx8 v = cvt8(Wo + (size_t)(tn + row) * 512 + kt * 64 + t8 * 8);
      *(bfx8*)&Bs[row * 64 + ((t8 ^ (row & 7)) << 3)] = v;
    }
    const bf16* asrc = Obsw + ((size_t)((tm >> 6) * 8 + kt) << 12);
#pragma unroll
    for (int it = 0; it < 2; ++it) {
      int c = it * 256 + tid;
      *(bfx8*)&As[c * 8] = *(const bfx8*)(asrc + (size_t)c * 8);
    }
    __syncthreads();
#pragma unroll
    for (int ks = 0; ks < 2; ++ks) {
      bfx8 af[2], bfr[4];
#pragma unroll
      for (int i = 0; i < 2; ++i) {
        int ra = wm * 32 + i * 16 + lm;
        af[i] = *(const bfx8*)&As[ra * 64 + (((ks * 4 + lk) ^ (ra & 7)) << 3)];
      }
#pragma unroll
      for (int j = 0; j < 4; ++j) {
        int rb = wn * 64 + j * 16 + lm;
        bfr[j] = *(const bfx8*)&Bs[rb * 64 + (((ks * 4 + lk) ^ (rb & 7)) << 3)];
      }
#pragma unroll
      for (int i = 0; i < 2; ++i)
#pragma unroll
        for (int j = 0; j < 4; ++j)
          acc[i][j] = mfma16(af[i], bfr[j], acc[i][j]);
    }
    __syncthreads();
  }
#pragma unroll
  for (int i = 0; i < 2; ++i)
#pragma unroll
    for (int j = 0; j < 4; ++j)
#pragma unroll
      for (int r = 0; r < 4; ++r) {
        int m = tm + wm * 32 + i * 16 + lk * 4 + r;
        int n = tn + wn * 64 + j * 16 + lm;
        out[(size_t)m * 512 + n] = acc[i][j][r];
      }
}

// ---------------- launch ----------------
extern "C" void kernel_launch(void* const* d_in, const int* in_sizes, int n_in,
                              void* d_out, int out_size, void* d_ws, size_t ws_size,
                              hipStream_t stream) {
  (void)in_sizes; (void)n_in; (void)out_size; (void)ws_size;
  char* wsp = (char*)d_ws;
  const size_t MB = 1ull << 20;

  ProjArgs pa;
  pa.Q = (const float*)d_in[0];
  pa.K = (const float*)d_in[1];
  pa.V = (const float*)d_in[2];
  pa.Wq = (const float*)d_in[3];
  pa.Wk = (const float*)d_in[4];
  pa.Wv = (const float*)d_in[5];
  pa.Qimg = (bf16*)(wsp + 0 * MB);
  pa.Kimg = (bf16*)(wsp + 4 * MB);
  pa.Vimg = (bf16*)(wsp + 8 * MB);
  pa.KVb = (bf16*)(wsp + 16 * MB);
  pa.ksums = (float*)(wsp + 20 * MB);
  bf16* Obsw = (bf16*)(wsp + 12 * MB);

  proj_fused<<<512, 256, 0, stream>>>(pa);
  chunk_out<<<dim3(32, 16), 256, 0, stream>>>(pa.Qimg, pa.Kimg, pa.Vimg, pa.KVb,
                                              pa.ksums, Obsw);
  out_gemm<<<256, 256, 0, stream>>>(Obsw, (const float*)d_in[6], (float*)d_out);
}